// Round 13
// baseline (145.774 us; speedup 1.0000x reference)
//
#include <hip/hip_runtime.h>

namespace {
constexpr int Kc = 32, HIDc = 32, NBc = 10;
constexpr float C_S = 0.3826834323650898f;   // sin(pi/8)
constexpr float C_X = 0.9238795325112867f;   // cos(pi/8)
constexpr float SQ3 = 1.7320508075688772f;
constexpr float INV_SQRT_K   = 0.17677669529663687f;  // 1/sqrt(32)
constexpr float INV_SQRT_HID = 0.17677669529663687f;  // 1/sqrt(32)
constexpr float INV_SQRT_NB  = 0.31622776601683794f;  // 1/sqrt(10)
constexpr float INV_SQRT_2HID = 0.125f;               // 1/sqrt(64)
constexpr float INV_STEP  = 1.8f;                     // 1/(5/9)
constexpr float EMB_SCALE = 0.8928571428571429f;      // 1/1.12

constexpr int   TABN   = 2048;
constexpr float TSCALE = 2047.0f / 5.0f;             // index scale over [0,5]

__device__ __forceinline__ float silu_div(float x) {
    return x / (1.0f + __expf(-x));
}
__device__ __forceinline__ float silu_rcp(float x) {
    return x * __builtin_amdgcn_rcpf(1.0f + __expf(-x));
}
} // namespace

// ---------------------------------------------------------------------------
// Build kernel (256 blocks, 8 table rows each):
//  A: per-block LDS MsTp/MvTp fold matrices (padded 33 to kill bank conflicts)
//     MsT[v][u] = Sum_j (W2f2[u*64+j]*c2a[j]) * lin1s[v*32+j]  (Mv analog)
//  B: w1tab row pair (fc1 radial) + w2 row (fc2 h2) -- R9-verified MLP chains
//  C: gS[i][v] = Sum_u w2row[i][u]*MsT[v][u],  gV analog
// phase2 then needs only gS/gV lerp + raw H[src] -- phase1's fold loop dies.
// ---------------------------------------------------------------------------
__global__ __launch_bounds__(256) void se3_build(
    const float* __restrict__ f1w0, const float* __restrict__ f1w1,
    const float* __restrict__ f1w2,
    const float* __restrict__ f2w0, const float* __restrict__ f2w1,
    const float* __restrict__ lin1s, const float* __restrict__ lin1v,
    const float* __restrict__ W2f2,
    const float* __restrict__ c2a, const float* __restrict__ c2b,
    float* __restrict__ w1tab, float* __restrict__ gS, float* __restrict__ gV)
{
    __shared__ float Wa[32 * 33];     // [u][j] padded
    __shared__ float Wb[32 * 33];
    __shared__ float MsTp[32 * 33];   // [v][u] padded
    __shared__ float MvTp[32 * 33];
    __shared__ float w2row[8][33];

    const int tid = threadIdx.x;
    const int row = tid >> 5;                 // 8 rows per block
    const int u   = tid & 31;
    const int i   = blockIdx.x * 8 + row;     // table row index

    // ---- A1: weight*scale products into LDS ----
#pragma unroll
    for (int k = 0; k < 4; ++k) {
        const int id = tid + 256 * k;         // 0..1023
        const int uu = id >> 5, j = id & 31;
        Wa[uu * 33 + j] = W2f2[uu * 64 + j]      * c2a[j];
        Wb[uu * 33 + j] = W2f2[uu * 64 + 32 + j] * c2b[j];
    }
    __syncthreads();

    // ---- A2: MsTp/MvTp ----
#pragma unroll
    for (int k = 0; k < 4; ++k) {
        const int id = tid + 256 * k;         // 0..1023
        const int v = id >> 5, uu = id & 31;
        float aS = 0.f, aV = 0.f;
#pragma unroll
        for (int j = 0; j < 32; ++j) {
            aS = fmaf(Wa[uu * 33 + j], lin1s[v * 32 + j], aS);
            aV = fmaf(Wb[uu * 33 + j], lin1v[v * 32 + j], aV);
        }
        MsTp[v * 33 + uu] = aS;
        MvTp[v * 33 + uu] = aV;
    }

    // ---- B: MLP chains for this row (R9-verified, shuffle width 32) ----
    const float r = (float)i * (5.0f / 2047.0f);
    float emb[NBc];
#pragma unroll
    for (int b = 0; b < NBc; ++b) {
        const float d = r * INV_STEP - (float)b;
        emb[b] = __expf(-d * d) * EMB_SCALE;
    }

    // fc1 chain -> w1 pair
    float acc = 0.f;
#pragma unroll
    for (int b = 0; b < NBc; ++b) acc = fmaf(emb[b], f1w0[b * HIDc + u], acc);
    const float h1a = silu_div(acc * INV_SQRT_NB);
    acc = 0.f;
    for (int v = 0; v < HIDc; ++v)
        acc = fmaf(__shfl(h1a, v, 32), f1w1[v * HIDc + u], acc);
    const float h2a = silu_div(acc * INV_SQRT_HID);
    float wa = 0.f, wb = 0.f;
    for (int v = 0; v < HIDc; ++v) {
        const float hv = __shfl(h2a, v, 32);
        wa = fmaf(hv, f1w2[2 * v + 0], wa);
        wb = fmaf(hv, f1w2[2 * v + 1], wb);
    }
    if (u == 0) {
        w1tab[2 * i + 0] = wa * INV_SQRT_HID;
        w1tab[2 * i + 1] = wb * INV_SQRT_HID;
    }

    // fc2 chain -> h2 row (into LDS)
    acc = 0.f;
#pragma unroll
    for (int b = 0; b < NBc; ++b) acc = fmaf(emb[b], f2w0[b * HIDc + u], acc);
    const float g1 = silu_div(acc * INV_SQRT_NB);
    acc = 0.f;
    for (int v = 0; v < HIDc; ++v)
        acc = fmaf(__shfl(g1, v, 32), f2w1[v * HIDc + u], acc);
    w2row[row][u] = silu_div(acc * INV_SQRT_HID);

    __syncthreads();

    // ---- C: contract w2 row against MsT/MvT (lane = v) ----
    const int v = u;
    float s = 0.f, vv = 0.f;
#pragma unroll
    for (int uu = 0; uu < 32; ++uu) {
        const float h2u = w2row[row][uu];        // broadcast
        s  = fmaf(h2u, MsTp[v * 33 + uu], s);    // conflict-free (pad 33)
        vv = fmaf(h2u, MvTp[v * 33 + uu], vv);
    }
    gS[i * 32 + v] = s;
    gV[i * 32 + v] = vv;
}

// ---------------------------------------------------------------------------
// Phase 1 — R9-verified minus the fold loop: writes raw node vectors
// H[n][u] = (hs, hvx, hvy, hvz). No LDS, no MsT/MvT.
// ---------------------------------------------------------------------------
__global__ __launch_bounds__(256) void se3_phase1(
    const float* __restrict__ coords, const float* __restrict__ t,
    const int* __restrict__ esrc, const float* __restrict__ emask,
    const float* __restrict__ sc1_w, const float* __restrict__ lin1_w,
    const float* __restrict__ l2s, const float* __restrict__ l2v,
    const float* __restrict__ sc2_w,
    const float* __restrict__ w1tab,
    float4* __restrict__ H, float* __restrict__ out_scpart)
{
    const int e    = blockIdx.x * 256 + threadIdx.x;
    const int n    = e >> 5;
    const int u    = threadIdx.x & 31;
    const int src  = esrc[e];
    const float em = emask[e];

    const float dx = coords[3 * n + 0] - coords[3 * src + 0];
    const float dy = coords[3 * n + 1] - coords[3 * src + 1];
    const float dz = coords[3 * n + 2] - coords[3 * src + 2];
    const float r  = sqrtf(dx * dx + dy * dy + dz * dz + 1e-12f);
    const float ir = 1.0f / r;
    const float shx = SQ3 * dx * ir, shy = SQ3 * dy * ir, shz = SQ3 * dz * ir;

    // w1 via table lerp (float2 loads)
    const float x = fminf(r, 5.0f) * TSCALE;
    int i0 = (int)x; i0 = (i0 > TABN - 2) ? (TABN - 2) : i0;
    const float f = x - (float)i0;
    const float2* __restrict__ w1t2 = (const float2*)w1tab;
    const float2 wv0 = w1t2[i0];
    const float2 wv1 = w1t2[i0 + 1];
    const float w10 = fmaf(f, wv1.x - wv0.x, wv0.x);   // 1/sqrt(HID) folded
    const float w11 = fmaf(f, wv1.y - wv0.y, wv0.y);

    const float xs = t[src >> 8] * lin1_w[0];          // batch[i] == i>>8
    float ms = w10 * xs * em;
    const float fv = w11 * xs * em;
    float mvx = fv * shx, mvy = fv * shy, mvz = fv * shz;

#pragma unroll
    for (int m = 16; m >= 1; m >>= 1) {
        ms  += __shfl_xor(ms,  m, 32);
        mvx += __shfl_xor(mvx, m, 32);
        mvy += __shfl_xor(mvy, m, 32);
        mvz += __shfl_xor(mvz, m, 32);
    }
    const float nms = ms  * INV_SQRT_K;
    const float nvx = mvx * INV_SQRT_K;
    const float nvy = mvy * INV_SQRT_K;
    const float nvz = mvz * INV_SQRT_K;

    // ---- node phase: lane owns hidden unit u of node n ----
    const float a  = t[n >> 8];
    const float hs = silu_rcp(C_S * a * sc1_w[u] + C_X * nms * a * l2s[u]);
    const float lv = l2v[u];
    const float hvx = silu_rcp(C_X * nvx * a * lv);
    const float hvy = silu_rcp(C_X * nvy * a * lv);
    const float hvz = silu_rcp(C_X * nvz * a * lv);

    const float s2 = sc2_w[u];
    float scx = hvx * s2, scy = hvy * s2, scz = hvz * s2;
#pragma unroll
    for (int m = 16; m >= 1; m >>= 1) {
        scx += __shfl_xor(scx, m, 32);
        scy += __shfl_xor(scy, m, 32);
        scz += __shfl_xor(scz, m, 32);
    }

    H[n * HIDc + u] = make_float4(hs, hvx, hvy, hvz);

    if (u == 0) {
        const float s = C_S * a * INV_SQRT_HID;
        out_scpart[3 * n + 0] = scx * s;
        out_scpart[3 * n + 1] = scy * s;
        out_scpart[3 * n + 2] = scz * s;
    }
}

// ---------------------------------------------------------------------------
// Phase 2 — gS/gV lerp (L2-hot rows) dotted with H[src]; scale by a_src/32.
// p = (a_src/32) Sum_v gSl[v]*hs[src][v];  q_c = (a_src/32) Sum_v gVl[v]*hv_c.
// ---------------------------------------------------------------------------
__global__ __launch_bounds__(256) void se3_phase2(
    const float* __restrict__ coords, const float* __restrict__ t,
    const int* __restrict__ esrc, const float* __restrict__ emask,
    const float* __restrict__ gS, const float* __restrict__ gV,
    const float4* __restrict__ H, float* __restrict__ out)
{
    const int e    = blockIdx.x * 256 + threadIdx.x;
    const int n    = e >> 5;
    const int u    = threadIdx.x & 31;
    const int src  = esrc[e];
    const float em = emask[e];

    const float dx = coords[3 * n + 0] - coords[3 * src + 0];
    const float dy = coords[3 * n + 1] - coords[3 * src + 1];
    const float dz = coords[3 * n + 2] - coords[3 * src + 2];
    const float r  = sqrtf(dx * dx + dy * dy + dz * dz + 1e-12f);
    const float ir = 1.0f / r;
    const float shx = SQ3 * dx * ir, shy = SQ3 * dy * ir, shz = SQ3 * dz * ir;

    float p = 0.f, qx = 0.f, qy = 0.f, qz = 0.f;
    float asc = 0.f;
    if (em != 0.0f) {
        asc = t[src >> 8] * (1.0f / 32.0f);
        const float x = fminf(r, 5.0f) * TSCALE;
        int i0 = (int)x; i0 = (i0 > TABN - 2) ? (TABN - 2) : i0;
        const float f = x - (float)i0;
        const float4* __restrict__ sa = (const float4*)(gS + i0 * HIDc);
        const float4* __restrict__ sb = sa + 8;
        const float4* __restrict__ va = (const float4*)(gV + i0 * HIDc);
        const float4* __restrict__ vb = va + 8;
        const float4* __restrict__ hp = H + src * HIDc;
#pragma unroll
        for (int q = 0; q < 8; ++q) {
            const float4 s0 = sa[q], s1 = sb[q];
            const float4 v0 = va[q], v1 = vb[q];
            const float sl0 = fmaf(f, s1.x - s0.x, s0.x);
            const float sl1 = fmaf(f, s1.y - s0.y, s0.y);
            const float sl2 = fmaf(f, s1.z - s0.z, s0.z);
            const float sl3 = fmaf(f, s1.w - s0.w, s0.w);
            const float vl0 = fmaf(f, v1.x - v0.x, v0.x);
            const float vl1 = fmaf(f, v1.y - v0.y, v0.y);
            const float vl2 = fmaf(f, v1.z - v0.z, v0.z);
            const float vl3 = fmaf(f, v1.w - v0.w, v0.w);
            const float4 g0 = hp[4 * q + 0];
            const float4 g1 = hp[4 * q + 1];
            const float4 g2 = hp[4 * q + 2];
            const float4 g3 = hp[4 * q + 3];
            p  = fmaf(sl0, g0.x, p);  qx = fmaf(vl0, g0.y, qx);
            qy = fmaf(vl0, g0.z, qy); qz = fmaf(vl0, g0.w, qz);
            p  = fmaf(sl1, g1.x, p);  qx = fmaf(vl1, g1.y, qx);
            qy = fmaf(vl1, g1.z, qy); qz = fmaf(vl1, g1.w, qz);
            p  = fmaf(sl2, g2.x, p);  qx = fmaf(vl2, g2.y, qx);
            qy = fmaf(vl2, g2.z, qy); qz = fmaf(vl2, g2.w, qz);
            p  = fmaf(sl3, g3.x, p);  qx = fmaf(vl3, g3.y, qx);
            qy = fmaf(vl3, g3.z, qy); qz = fmaf(vl3, g3.w, qz);
        }
    }

    const float sc = em * asc;
    float cx = sc * fmaf(p, shx, qx);
    float cy = sc * fmaf(p, shy, qy);
    float cz = sc * fmaf(p, shz, qz);
#pragma unroll
    for (int m = 16; m >= 1; m >>= 1) {
        cx += __shfl_xor(cx, m, 32);
        cy += __shfl_xor(cy, m, 32);
        cz += __shfl_xor(cz, m, 32);
    }

    if (u == 0) {
        const float a = t[n >> 8];
        const float s = C_X * a * INV_SQRT_2HID * INV_SQRT_K;
        out[3 * n + 0] = out[3 * n + 0] + cx * s;
        out[3 * n + 1] = out[3 * n + 1] + cy * s;
        out[3 * n + 2] = out[3 * n + 2] + cz * s;
    }
}

extern "C" void kernel_launch(void* const* d_in, const int* in_sizes, int n_in,
                              void* d_out, int out_size, void* d_ws, size_t ws_size,
                              hipStream_t stream) {
    const float* coords = (const float*)d_in[0];
    const float* t      = (const float*)d_in[1];
    const int*   esrc   = (const int*)d_in[3];
    const float* emask  = (const float*)d_in[5];
    const float* sc1_w  = (const float*)d_in[6];
    const float* lin1_w = (const float*)d_in[7];
    const float* fc1_w0 = (const float*)d_in[8];
    const float* fc1_w1 = (const float*)d_in[9];
    const float* fc1_w2 = (const float*)d_in[10];
    const float* c1l2s  = (const float*)d_in[11];
    const float* c1l2v  = (const float*)d_in[12];
    const float* sc2_w  = (const float*)d_in[13];
    const float* lin1s  = (const float*)d_in[14];
    const float* lin1v  = (const float*)d_in[15];
    const float* fc2_w0 = (const float*)d_in[16];
    const float* fc2_w1 = (const float*)d_in[17];
    const float* fc2_w2 = (const float*)d_in[18];
    const float* c2a    = (const float*)d_in[19];
    const float* c2b    = (const float*)d_in[20];

    float*  out = (float*)d_out;
    float4* H   = (float4*)d_ws;                          // 8 MB
    float*  aux = (float*)((char*)d_ws + 16384 * 32 * 16);
    float*  w1tab = aux;                                  // 4096 f
    float*  gS    = aux + 4096;                           // 65536 f
    float*  gV    = aux + 4096 + 65536;                   // 65536 f

    const int nEdges = 16384 * Kc;         // 524288
    dim3 block(256);
    dim3 grid(nEdges / 256);               // 2048 blocks

    se3_build<<<dim3(256), block, 0, stream>>>(
        fc1_w0, fc1_w1, fc1_w2, fc2_w0, fc2_w1,
        lin1s, lin1v, fc2_w2, c2a, c2b, w1tab, gS, gV);

    se3_phase1<<<grid, block, 0, stream>>>(coords, t, esrc, emask,
        sc1_w, lin1_w, c1l2s, c1l2v, sc2_w, w1tab, H, out);

    se3_phase2<<<grid, block, 0, stream>>>(coords, t, esrc, emask,
        gS, gV, H, out);
}

// Round 14
// 134.070 us; speedup vs baseline: 1.0873x; 1.0873x over previous
//
#include <hip/hip_runtime.h>

namespace {
constexpr int Kc = 32, HIDc = 32, NBc = 10;
constexpr float C_S = 0.3826834323650898f;   // sin(pi/8)
constexpr float C_X = 0.9238795325112867f;   // cos(pi/8)
constexpr float SQ3 = 1.7320508075688772f;
constexpr float INV_SQRT_K   = 0.17677669529663687f;  // 1/sqrt(32)
constexpr float INV_SQRT_HID = 0.17677669529663687f;  // 1/sqrt(32)
constexpr float INV_SQRT_NB  = 0.31622776601683794f;  // 1/sqrt(10)
constexpr float INV_SQRT_2HID = 0.125f;               // 1/sqrt(64)
constexpr float INV_STEP  = 1.8f;                     // 1/(5/9)
constexpr float EMB_SCALE = 0.8928571428571429f;      // 1/1.12

constexpr int   TABN   = 2048;
constexpr float TSCALE = 2047.0f / 5.0f;             // index scale over [0,5]

__device__ __forceinline__ float silu_div(float x) {
    return x / (1.0f + __expf(-x));
}
__device__ __forceinline__ float silu_rcp(float x) {
    return x * __builtin_amdgcn_rcpf(1.0f + __expf(-x));
}
} // namespace

// ---------------------------------------------------------------------------
// Build kernel (one launch, 264 blocks):
//  blocks 0..255 : radial tables. Row i (r_i = 5*i/2047), 32 lanes per row:
//     w1tab[i][0..1] = _radial_fc1(emb(r_i))            (exact f32 MLP)
//     w2tab[i][0..31] = h2_fc2(r_i) = silu((silu(emb@W0/sN)@W1)/sH)
//  blocks 256..263: MsT/MvT fold matrices:
//     MsT[v*32+u] = Sum_j W2f2[u*64+j]   *c2a[j]*lin1s[v*32+j]
//     MvT[v*32+u] = Sum_j W2f2[u*64+32+j]*c2b[j]*lin1v[v*32+j]
// ---------------------------------------------------------------------------
__global__ __launch_bounds__(256) void se3_build(
    const float* __restrict__ f1w0, const float* __restrict__ f1w1,
    const float* __restrict__ f1w2,
    const float* __restrict__ f2w0, const float* __restrict__ f2w1,
    const float* __restrict__ lin1s, const float* __restrict__ lin1v,
    const float* __restrict__ W2f2,
    const float* __restrict__ c2a, const float* __restrict__ c2b,
    float* __restrict__ w1tab, float* __restrict__ w2tab,
    float* __restrict__ MsT, float* __restrict__ MvT)
{
    if (blockIdx.x < 256) {
        const int gid = blockIdx.x * 256 + threadIdx.x;
        const int i = gid >> 5;
        const int u = gid & 31;
        const float r = (float)i * (5.0f / 2047.0f);

        float emb[NBc];
#pragma unroll
        for (int b = 0; b < NBc; ++b) {
            const float d = r * INV_STEP - (float)b;
            emb[b] = __expf(-d * d) * EMB_SCALE;
        }

        // fc1 chain -> w1 pair
        float acc = 0.f;
#pragma unroll
        for (int b = 0; b < NBc; ++b) acc = fmaf(emb[b], f1w0[b * HIDc + u], acc);
        const float h1a = silu_div(acc * INV_SQRT_NB);
        acc = 0.f;
        for (int v = 0; v < HIDc; ++v)
            acc = fmaf(__shfl(h1a, v, 32), f1w1[v * HIDc + u], acc);
        const float h2a = silu_div(acc * INV_SQRT_HID);
        float wa = 0.f, wb = 0.f;
        for (int v = 0; v < HIDc; ++v) {
            const float hv = __shfl(h2a, v, 32);
            wa = fmaf(hv, f1w2[2 * v + 0], wa);
            wb = fmaf(hv, f1w2[2 * v + 1], wb);
        }
        if (u == 0) {
            w1tab[2 * i + 0] = wa * INV_SQRT_HID;
            w1tab[2 * i + 1] = wb * INV_SQRT_HID;
        }

        // fc2 chain -> h2 row
        acc = 0.f;
#pragma unroll
        for (int b = 0; b < NBc; ++b) acc = fmaf(emb[b], f2w0[b * HIDc + u], acc);
        const float g1 = silu_div(acc * INV_SQRT_NB);
        acc = 0.f;
        for (int v = 0; v < HIDc; ++v)
            acc = fmaf(__shfl(g1, v, 32), f2w1[v * HIDc + u], acc);
        w2tab[i * HIDc + u] = silu_div(acc * INV_SQRT_HID);
    } else {
        const int id = (blockIdx.x - 256) * 256 + threadIdx.x;   // 0..2047
        const int v = (id & 1023) >> 5;
        const int u = id & 31;
        float acc = 0.f;
        if (id < 1024) {
#pragma unroll
            for (int j = 0; j < 32; ++j)
                acc = fmaf(W2f2[u * 64 + j] * c2a[j], lin1s[v * 32 + j], acc);
            MsT[v * 32 + u] = acc;
        } else {
#pragma unroll
            for (int j = 0; j < 32; ++j)
                acc = fmaf(W2f2[u * 64 + 32 + j] * c2b[j], lin1v[v * 32 + j], acc);
            MvT[v * 32 + u] = acc;
        }
    }
}

// ---------------------------------------------------------------------------
// Phase 1: per edge, w1 via table lerp -> butterfly segment sums ->
// node phase (Hsh broadcast + MsT/MvT fold) -> tab2, sc_v out.
// ---------------------------------------------------------------------------
__global__ __launch_bounds__(256) void se3_phase1(
    const float* __restrict__ coords, const float* __restrict__ t,
    const int* __restrict__ batch, const int* __restrict__ esrc,
    const float* __restrict__ emask,
    const float* __restrict__ sc1_w, const float* __restrict__ lin1_w,
    const float* __restrict__ l2s, const float* __restrict__ l2v,
    const float* __restrict__ sc2_w,
    const float* __restrict__ w1tab,
    const float* __restrict__ MsT, const float* __restrict__ MvT,
    float4* __restrict__ tab2, float* __restrict__ out_scpart)
{
    __shared__ float4 Hsh[4][2][32];     // [wave][half(node)][unit]

    const int e    = blockIdx.x * 256 + threadIdx.x;
    const int n    = e >> 5;
    const int u    = threadIdx.x & 31;
    const int h    = (threadIdx.x >> 5) & 1;
    const int widL = threadIdx.x >> 6;
    const int src  = esrc[e];
    const float em = emask[e];

    const float dx = coords[3 * n + 0] - coords[3 * src + 0];
    const float dy = coords[3 * n + 1] - coords[3 * src + 1];
    const float dz = coords[3 * n + 2] - coords[3 * src + 2];
    const float r  = sqrtf(dx * dx + dy * dy + dz * dz + 1e-12f);
    const float ir = 1.0f / r;
    const float shx = SQ3 * dx * ir, shy = SQ3 * dy * ir, shz = SQ3 * dz * ir;

    // w1 via table (valid edges have r < 5; masked edges clamped, em=0 kills them)
    const float x = fminf(r, 5.0f) * TSCALE;
    int i0 = (int)x; i0 = (i0 > TABN - 2) ? (TABN - 2) : i0;
    const float f = x - (float)i0;
    const float wA0 = w1tab[2 * i0 + 0], wA1 = w1tab[2 * i0 + 2];
    const float wB0 = w1tab[2 * i0 + 1], wB1 = w1tab[2 * i0 + 3];
    const float w10 = fmaf(f, wA1 - wA0, wA0);   // 1/sqrt(HID) already folded
    const float w11 = fmaf(f, wB1 - wB0, wB0);

    const float xs = t[batch[src]] * lin1_w[0];
    float ms = w10 * xs * em;
    const float fv = w11 * xs * em;
    float mvx = fv * shx, mvy = fv * shy, mvz = fv * shz;

#pragma unroll
    for (int m = 16; m >= 1; m >>= 1) {
        ms  += __shfl_xor(ms,  m, 32);
        mvx += __shfl_xor(mvx, m, 32);
        mvy += __shfl_xor(mvy, m, 32);
        mvz += __shfl_xor(mvz, m, 32);
    }
    const float nms = ms  * INV_SQRT_K;
    const float nvx = mvx * INV_SQRT_K;
    const float nvy = mvy * INV_SQRT_K;
    const float nvz = mvz * INV_SQRT_K;

    // ---- node phase: lane owns hidden unit u of node n ----
    const float a  = t[batch[n]];
    const float hs = silu_rcp(C_S * a * sc1_w[u] + C_X * nms * a * l2s[u]);
    const float lv = l2v[u];
    const float hvx = silu_rcp(C_X * nvx * a * lv);
    const float hvy = silu_rcp(C_X * nvy * a * lv);
    const float hvz = silu_rcp(C_X * nvz * a * lv);

    const float s2 = sc2_w[u];
    float scx = hvx * s2, scy = hvy * s2, scz = hvz * s2;
#pragma unroll
    for (int m = 16; m >= 1; m >>= 1) {
        scx += __shfl_xor(scx, m, 32);
        scy += __shfl_xor(scy, m, 32);
        scz += __shfl_xor(scz, m, 32);
    }

    Hsh[widL][h][u] = make_float4(hs, hvx, hvy, hvz);

    float tA = 0.f, tBx = 0.f, tBy = 0.f, tBz = 0.f;
    for (int v = 0; v < HIDc; ++v) {
        const float4 hv4 = Hsh[widL][h][v];
        const float msw = MsT[v * 32 + u];
        const float mvw = MvT[v * 32 + u];
        tA  = fmaf(hv4.x, msw, tA);
        tBx = fmaf(hv4.y, mvw, tBx);
        tBy = fmaf(hv4.z, mvw, tBy);
        tBz = fmaf(hv4.w, mvw, tBz);
    }
    const float sc_ = a * (1.0f / 32.0f);
    float4 t2;
    t2.x = tA  * sc_;
    t2.y = tBx * sc_;
    t2.z = tBy * sc_;
    t2.w = tBz * sc_;
    tab2[n * HIDc + u] = t2;

    if (u == 0) {
        const float s = C_S * a * INV_SQRT_HID;
        out_scpart[3 * n + 0] = scx * s;
        out_scpart[3 * n + 1] = scy * s;
        out_scpart[3 * n + 2] = scz * s;
    }
}

// ---------------------------------------------------------------------------
// Phase 2: per edge, h2_fc2 via table lerp, p/q = dot with tab2[src],
// width-32 butterfly, lane0 RMW into out. Gather skipped when em==0.
// ---------------------------------------------------------------------------
__global__ __launch_bounds__(256) void se3_phase2(
    const float* __restrict__ coords, const float* __restrict__ t,
    const int* __restrict__ esrc, const float* __restrict__ emask,
    const float* __restrict__ w2tab,
    const float4* __restrict__ tab2, float* __restrict__ out)
{
    const int e    = blockIdx.x * 256 + threadIdx.x;
    const int n    = e >> 5;
    const int u    = threadIdx.x & 31;
    const int src  = esrc[e];
    const float em = emask[e];

    const float dx = coords[3 * n + 0] - coords[3 * src + 0];
    const float dy = coords[3 * n + 1] - coords[3 * src + 1];
    const float dz = coords[3 * n + 2] - coords[3 * src + 2];
    const float r  = sqrtf(dx * dx + dy * dy + dz * dz + 1e-12f);
    const float ir = 1.0f / r;
    const float shx = SQ3 * dx * ir, shy = SQ3 * dy * ir, shz = SQ3 * dz * ir;

    float p = 0.f, qx = 0.f, qy = 0.f, qz = 0.f;
    if (em != 0.0f) {
        const float x = fminf(r, 5.0f) * TSCALE;
        int i0 = (int)x; i0 = (i0 > TABN - 2) ? (TABN - 2) : i0;
        const float f = x - (float)i0;
        const float4* __restrict__ ra = (const float4*)(w2tab + i0 * HIDc);
        const float4* __restrict__ rb = ra + 8;
        const float4* __restrict__ tp = tab2 + src * HIDc;
#pragma unroll
        for (int q = 0; q < 8; ++q) {
            const float4 h0 = ra[q];
            const float4 h1 = rb[q];
            const float hx0 = fmaf(f, h1.x - h0.x, h0.x);
            const float hx1 = fmaf(f, h1.y - h0.y, h0.y);
            const float hx2 = fmaf(f, h1.z - h0.z, h0.z);
            const float hx3 = fmaf(f, h1.w - h0.w, h0.w);
            const float4 g0 = tp[4 * q + 0];
            const float4 g1 = tp[4 * q + 1];
            const float4 g2 = tp[4 * q + 2];
            const float4 g3 = tp[4 * q + 3];
            p  = fmaf(hx0, g0.x, p);  qx = fmaf(hx0, g0.y, qx);
            qy = fmaf(hx0, g0.z, qy); qz = fmaf(hx0, g0.w, qz);
            p  = fmaf(hx1, g1.x, p);  qx = fmaf(hx1, g1.y, qx);
            qy = fmaf(hx1, g1.z, qy); qz = fmaf(hx1, g1.w, qz);
            p  = fmaf(hx2, g2.x, p);  qx = fmaf(hx2, g2.y, qx);
            qy = fmaf(hx2, g2.z, qy); qz = fmaf(hx2, g2.w, qz);
            p  = fmaf(hx3, g3.x, p);  qx = fmaf(hx3, g3.y, qx);
            qy = fmaf(hx3, g3.z, qy); qz = fmaf(hx3, g3.w, qz);
        }
    }

    float cx = em * fmaf(p, shx, qx);
    float cy = em * fmaf(p, shy, qy);
    float cz = em * fmaf(p, shz, qz);
#pragma unroll
    for (int m = 16; m >= 1; m >>= 1) {
        cx += __shfl_xor(cx, m, 32);
        cy += __shfl_xor(cy, m, 32);
        cz += __shfl_xor(cz, m, 32);
    }

    if (u == 0) {
        const float a = t[n >> 8];
        const float s = C_X * a * INV_SQRT_2HID * INV_SQRT_K;
        out[3 * n + 0] = out[3 * n + 0] + cx * s;
        out[3 * n + 1] = out[3 * n + 1] + cy * s;
        out[3 * n + 2] = out[3 * n + 2] + cz * s;
    }
}

extern "C" void kernel_launch(void* const* d_in, const int* in_sizes, int n_in,
                              void* d_out, int out_size, void* d_ws, size_t ws_size,
                              hipStream_t stream) {
    const float* coords = (const float*)d_in[0];
    const float* t      = (const float*)d_in[1];
    const int*   batch  = (const int*)d_in[2];
    const int*   esrc   = (const int*)d_in[3];
    const float* emask  = (const float*)d_in[5];
    const float* sc1_w  = (const float*)d_in[6];
    const float* lin1_w = (const float*)d_in[7];
    const float* fc1_w0 = (const float*)d_in[8];
    const float* fc1_w1 = (const float*)d_in[9];
    const float* fc1_w2 = (const float*)d_in[10];
    const float* c1l2s  = (const float*)d_in[11];
    const float* c1l2v  = (const float*)d_in[12];
    const float* sc2_w  = (const float*)d_in[13];
    const float* lin1s  = (const float*)d_in[14];
    const float* lin1v  = (const float*)d_in[15];
    const float* fc2_w0 = (const float*)d_in[16];
    const float* fc2_w1 = (const float*)d_in[17];
    const float* fc2_w2 = (const float*)d_in[18];
    const float* c2a    = (const float*)d_in[19];
    const float* c2b    = (const float*)d_in[20];

    float*  out  = (float*)d_out;
    float4* tab2 = (float4*)d_ws;                         // 8 MB
    float*  aux  = (float*)((char*)d_ws + 16384 * 32 * 16);
    float*  MsT   = aux;                                  // 1024 f
    float*  MvT   = aux + 1024;                           // 1024 f
    float*  w1tab = aux + 2048;                           // 4096 f
    float*  w2tab = aux + 6144;                           // 65536 f

    const int nEdges = 16384 * Kc;         // 524288
    dim3 block(256);
    dim3 grid(nEdges / 256);               // 2048 blocks

    se3_build<<<dim3(264), block, 0, stream>>>(
        fc1_w0, fc1_w1, fc1_w2, fc2_w0, fc2_w1,
        lin1s, lin1v, fc2_w2, c2a, c2b, w1tab, w2tab, MsT, MvT);

    se3_phase1<<<grid, block, 0, stream>>>(coords, t, batch, esrc, emask,
        sc1_w, lin1_w, c1l2s, c1l2v, sc2_w, w1tab, MsT, MvT, tab2, out);

    se3_phase2<<<grid, block, 0, stream>>>(coords, t, esrc, emask,
        w2tab, tab2, out);
}